// Round 12
// baseline (148.704 us; speedup 1.0000x reference)
//
#include <hip/hip_runtime.h>

#define N_NODES 50000
#define N_EDGES 800000
#define NB      391            // buckets: dst>>7 (128 nodes each)
#define NBP     392            // padded bucket count (pad col stays zero)
#define G       128            // partition blocks for count/scatter
#define SCAN_N  (NBP * G)      // 50176 = 49 * 1024
#define SCAN_BLOCKS 49
#define MAXB    3072           // max edges per bucket (mean 2046, sigma ~45)

typedef _Float16 h2v __attribute__((ext_vector_type(2)));
typedef _Float16 h8v __attribute__((ext_vector_type(8)));
typedef float    f4v __attribute__((ext_vector_type(4)));

union H2U { h2v h; unsigned u; };            // packed f16 pair <-> dword
union H8U { h8v v; unsigned u[4]; };         // 8 f16 <-> 4 dwords

// ---------------------------------------------------------------------------
// Prep: cast x -> f16 + pack W1/W2 into MFMA B-fragment order (block 0 only).
// B-frag (16x16x32 f16): lane holds 8 f16 B[k=32kt+(lane>>4)*8+j][n=16nt+(lane&15)].
// ---------------------------------------------------------------------------
__global__ void prep_kernel(const float* __restrict__ x,
                            const float* __restrict__ W1_l,
                            const float* __restrict__ W1_r,
                            const float* __restrict__ W2_l,
                            const float* __restrict__ W2_r,
                            _Float16* __restrict__ xf,
                            _Float16* __restrict__ B1,
                            _Float16* __restrict__ B2) {
    const int tid = blockIdx.x * 256 + threadIdx.x;      // < 800000
    {   // cast 4 floats -> 4 f16
        float4 v = *(const float4*)(x + tid * 4);
        H2U a, b;
        a.h = h2v{ (_Float16)v.x, (_Float16)v.y };
        b.h = h2v{ (_Float16)v.z, (_Float16)v.w };
        uint2 o = { a.u, b.u };
        *(uint2*)(xf + tid * 4) = o;
    }
    if (blockIdx.x == 0) {
        const int t = threadIdx.x;
        // B1: [W1_l; W1_r] (128 x 64), 16 frags (kt 0..3, nt 0..3)
        for (int p = t; p < 16 * 512; p += 256) {
            const int frag = p >> 9, lane = (p >> 3) & 63, j = p & 7;
            const int kt = frag >> 2, nt = frag & 3;
            const int k = kt * 32 + (lane >> 4) * 8 + j;
            const int n = nt * 16 + (lane & 15);
            const float w = (k < 64) ? W1_l[k * 64 + n] : W1_r[(k - 64) * 64 + n];
            B1[p] = (_Float16)w;
        }
        // B2: [W2_l | W2_r] (64 x 32), 4 frags (kt 0..1, nt 0..1)
        for (int p = t; p < 4 * 512; p += 256) {
            const int frag = p >> 9, lane = (p >> 3) & 63, j = p & 7;
            const int kt = frag >> 1, nt = frag & 1;
            const int k = kt * 32 + (lane >> 4) * 8 + j;
            const int n = lane & 15;
            const float w = (nt == 0) ? W2_l[k * 16 + n] : W2_r[k * 16 + n];
            B2[p] = (_Float16)w;
        }
    }
}

// ---------------------------------------------------------------------------
// Partition pass 1: per-block LDS histogram of dst buckets, written
// TRANSPOSED (histT[bucket*G + block]) so the fused scan reads linearly.
// ---------------------------------------------------------------------------
__global__ __launch_bounds__(512) void count_kernel(const int* __restrict__ dst,
                                                    int* __restrict__ histT) {
    __shared__ int hist[NBP];
    const int b = blockIdx.x, t = threadIdx.x;
    for (int i = t; i < NBP; i += 512) hist[i] = 0;
    __syncthreads();
    for (int i4 = b * 512 + t; i4 < N_EDGES / 4; i4 += G * 512) {
        int4 d = *(const int4*)(dst + i4 * 4);
        atomicAdd(&hist[d.x >> 7], 1);
        atomicAdd(&hist[d.y >> 7], 1);
        atomicAdd(&hist[d.z >> 7], 1);
        atomicAdd(&hist[d.w >> 7], 1);
    }
    __syncthreads();
    for (int i = t; i < NB; i += 512) histT[i * G + b] = hist[i];
}

// ---------------------------------------------------------------------------
// Fused scan (was scanA+scanC): block b computes its base by summing
// histT[0 .. b*1024) coalesced (L2-resident, <=200KB), then LDS-scans its
// own 1024-elem chunk and emits offT = exclusive prefix.
// ---------------------------------------------------------------------------
__global__ void scan_kernel(const int* __restrict__ histT,
                            int* __restrict__ offT) {
    __shared__ int redu[256];
    __shared__ int lds[256];
    const int b = blockIdx.x, t = threadIdx.x;

    int part = 0;
    for (int j = t * 4; j < b * 1024; j += 1024) {
        int4 v = *(const int4*)(histT + j);
        part += v.x + v.y + v.z + v.w;
    }
    redu[t] = part;
    __syncthreads();
    for (int off = 128; off > 0; off >>= 1) {
        if (t < off) redu[t] += redu[t + off];
        __syncthreads();
    }
    const int base = redu[0];

    const int idx = b * 1024 + t * 4;
    int4 v = *(const int4*)(histT + idx);
    const int s = v.x + v.y + v.z + v.w;
    lds[t] = s;
    __syncthreads();
    for (int off = 1; off < 256; off <<= 1) {
        int u = (t >= off) ? lds[t - off] : 0;
        __syncthreads();
        lds[t] += u;
        __syncthreads();
    }
    const int excl = base + lds[t] - s;
    int4 o = { excl, excl + v.x, excl + v.x + v.y, excl + v.x + v.y + v.z };
    *(int4*)(offT + idx) = o;
}

// ---------------------------------------------------------------------------
// Partition pass 2: scatter edges to exact positions via LDS cursors seeded
// from offT — zero global atomics. Packs (dst&127)<<16 | src.
// ---------------------------------------------------------------------------
__global__ __launch_bounds__(512) void scatter_kernel(const int* __restrict__ src,
                                                      const int* __restrict__ dst,
                                                      const int* __restrict__ offT,
                                                      int* __restrict__ bbuf) {
    __shared__ int cur[NB];
    const int b = blockIdx.x, t = threadIdx.x;
    for (int i = t; i < NB; i += 512) cur[i] = offT[i * G + b];
    __syncthreads();
    for (int i4 = b * 512 + t; i4 < N_EDGES / 4; i4 += G * 512) {
        int4 s = *(const int4*)(src + i4 * 4);
        int4 d = *(const int4*)(dst + i4 * 4);
        #pragma unroll
        for (int q = 0; q < 4; ++q) {
            const int dv = (q == 0) ? d.x : (q == 1) ? d.y : (q == 2) ? d.z : d.w;
            const int sv = (q == 0) ? s.x : (q == 1) ? s.y : (q == 2) ? s.z : s.w;
            const int pos = atomicAdd(&cur[dv >> 7], 1);
            bbuf[pos] = ((dv & 127) << 16) | sv;
        }
    }
}

// ---------------------------------------------------------------------------
// Build: one workgroup per bucket. Contiguous read of the bucket's packed
// edges, LDS hist over 128 local nodes, LDS scan -> rowptr, LDS scatter,
// fully-coalesced csr_src write-out.
// ---------------------------------------------------------------------------
__global__ __launch_bounds__(256) void build_kernel(
        const int* __restrict__ offT,
        const int* __restrict__ bbuf,
        int* __restrict__ csr_src,
        int* __restrict__ rowptr) {
    __shared__ int stash[MAXB];
    __shared__ int lcsr[MAXB];
    __shared__ int hist[128];
    __shared__ int cur[128];

    const int b = blockIdx.x, t = threadIdx.x;
    const int start = offT[b * G];
    const int end = offT[(b + 1) * G];     // valid for b=NB-1 via pad bucket
    const int cnt_b = min(end - start, MAXB);

    if (t < 128) hist[t] = 0;
    __syncthreads();

    for (int i = t; i < cnt_b; i += 256) {
        const int w = bbuf[start + i];
        stash[i] = w;
        atomicAdd(&hist[w >> 16], 1);
    }
    __syncthreads();

    const int orig = (t < 128) ? hist[t] : 0;
    for (int off = 1; off < 128; off <<= 1) {
        int v = (t >= off && t < 128) ? hist[t - off] : 0;
        __syncthreads();
        if (t < 128) hist[t] += v;
        __syncthreads();
    }
    if (t < 128) cur[t] = hist[t] - orig;    // exclusive
    __syncthreads();

    const int node = b * 128 + t;
    if (t < 128 && node < N_NODES) rowptr[node] = start + cur[t];
    if (b == NB - 1 && t == 0) rowptr[N_NODES] = N_EDGES;

    for (int i = t; i < cnt_b; i += 256) {
        const int w = stash[i];
        const int p = atomicAdd(&cur[w >> 16], 1);
        lcsr[p] = w & 0xFFFF;
    }
    __syncthreads();

    for (int i = t; i < cnt_b; i += 256) csr_src[start + i] = lcsr[i];
}

// ---------------------------------------------------------------------------
// FUSED layer 1 (gather + MLP). One wave = 16 nodes (block = 64 nodes).
// Lane l: cn = l&15 (its gather node in the tile), kq = l>>4 (feature quad).
// Each lane accumulates EXACTLY its MFMA A-fragment features
// ([8kq,8kq+8) and [32+8kq,32+8kq+8)) of node cn's neighbor mean, in packed
// f16 registers, over the node's full CSR range — mean lands directly in
// A-registers: no shfl reduce, no meanf round-trip. Then 16 MFMA (B1) ->
// h -> LDS (stride 72) -> 4 MFMA (B2) -> y2f, z.
// R10 lesson: per-lane register accumulation; NEVER per-edge LDS atomics.
// ---------------------------------------------------------------------------
__global__ __launch_bounds__(256) void layer1_kernel(
        const _Float16* __restrict__ xf,
        const int* __restrict__ rowptr,
        const int* __restrict__ csr_src,
        const _Float16* __restrict__ B1,
        const _Float16* __restrict__ B2,
        const float* __restrict__ b1,
        const float* __restrict__ b2,
        _Float16* __restrict__ y2f,
        float* __restrict__ z) {
    __shared__ _Float16 hlds[4][16 * 72];
    const int widx = threadIdx.x >> 6;
    const int l = threadIdx.x & 63;
    const int cn = l & 15;
    const int kq = l >> 4;
    const int n0 = (blockIdx.x * 4 + widx) * 16;
    const int ng = n0 + cn;                 // this lane's gather node

    int beg = 0, deg = 0;
    if (ng < N_NODES) {
        beg = rowptr[ng];
        deg = rowptr[ng + 1] - beg;
    }

    // ---- gather: accumulate this lane's A-fragment features ----
    H2U lo[4], hi[4];
    #pragma unroll
    for (int j = 0; j < 4; ++j) { lo[j].u = 0; hi[j].u = 0; }
    const _Float16* xq = xf + kq * 8;
    int i = 0;
    for (; i + 1 < deg; i += 2) {
        const int s0 = csr_src[beg + i];
        const int s1 = csr_src[beg + i + 1];
        const uint4 u0 = *(const uint4*)(xq + s0 * 64);
        const uint4 v0 = *(const uint4*)(xq + s0 * 64 + 32);
        const uint4 u1 = *(const uint4*)(xq + s1 * 64);
        const uint4 v1 = *(const uint4*)(xq + s1 * 64 + 32);
        H2U t;
        t.u = u0.x; lo[0].h += t.h;  t.u = u1.x; lo[0].h += t.h;
        t.u = u0.y; lo[1].h += t.h;  t.u = u1.y; lo[1].h += t.h;
        t.u = u0.z; lo[2].h += t.h;  t.u = u1.z; lo[2].h += t.h;
        t.u = u0.w; lo[3].h += t.h;  t.u = u1.w; lo[3].h += t.h;
        t.u = v0.x; hi[0].h += t.h;  t.u = v1.x; hi[0].h += t.h;
        t.u = v0.y; hi[1].h += t.h;  t.u = v1.y; hi[1].h += t.h;
        t.u = v0.z; hi[2].h += t.h;  t.u = v1.z; hi[2].h += t.h;
        t.u = v0.w; hi[3].h += t.h;  t.u = v1.w; hi[3].h += t.h;
    }
    if (i < deg) {
        const int s0 = csr_src[beg + i];
        const uint4 u0 = *(const uint4*)(xq + s0 * 64);
        const uint4 v0 = *(const uint4*)(xq + s0 * 64 + 32);
        H2U t;
        t.u = u0.x; lo[0].h += t.h;  t.u = v0.x; hi[0].h += t.h;
        t.u = u0.y; lo[1].h += t.h;  t.u = v0.y; hi[1].h += t.h;
        t.u = u0.z; lo[2].h += t.h;  t.u = v0.z; hi[2].h += t.h;
        t.u = u0.w; lo[3].h += t.h;  t.u = v0.w; hi[3].h += t.h;
    }
    const float rdeg = 1.0f / fmaxf((float)deg, 1.0f);
    const _Float16 rh = (_Float16)rdeg;
    const h2v rd2 = { rh, rh };
    H8U af0, af1, af2, af3;
    #pragma unroll
    for (int j = 0; j < 4; ++j) {
        lo[j].h *= rd2; hi[j].h *= rd2;
        af0.u[j] = lo[j].u;
        af1.u[j] = hi[j].u;
    }
    {   // self row (xf padded to 50048 rows so ng<50048 reads are in-bounds)
        const uint4 su = *(const uint4*)(xf + ng * 64 + kq * 8);
        const uint4 sv = *(const uint4*)(xf + ng * 64 + 32 + kq * 8);
        af2.u[0] = su.x; af2.u[1] = su.y; af2.u[2] = su.z; af2.u[3] = su.w;
        af3.u[0] = sv.x; af3.u[1] = sv.y; af3.u[2] = sv.z; af3.u[3] = sv.w;
    }

    // ---- h = relu([mean|x] @ [W1_l;W1_r] + b1): 16 MFMA ----
    const f4v zero = { 0.f, 0.f, 0.f, 0.f };
    f4v acc[4] = { zero, zero, zero, zero };
    #pragma unroll
    for (int nt = 0; nt < 4; ++nt) {
        acc[nt] = __builtin_amdgcn_mfma_f32_16x16x32_f16(af0.v, *(const h8v*)(B1 + ((0 * 4 + nt) * 64 + l) * 8), acc[nt], 0, 0, 0);
        acc[nt] = __builtin_amdgcn_mfma_f32_16x16x32_f16(af1.v, *(const h8v*)(B1 + ((1 * 4 + nt) * 64 + l) * 8), acc[nt], 0, 0, 0);
        acc[nt] = __builtin_amdgcn_mfma_f32_16x16x32_f16(af2.v, *(const h8v*)(B1 + ((2 * 4 + nt) * 64 + l) * 8), acc[nt], 0, 0, 0);
        acc[nt] = __builtin_amdgcn_mfma_f32_16x16x32_f16(af3.v, *(const h8v*)(B1 + ((3 * 4 + nt) * 64 + l) * 8), acc[nt], 0, 0, 0);
    }

    _Float16* hl = &hlds[widx][0];
    #pragma unroll
    for (int nt = 0; nt < 4; ++nt) {
        const float bias = b1[nt * 16 + cn];
        #pragma unroll
        for (int r = 0; r < 4; ++r) {
            const float hv = fmaxf(acc[nt][r] + bias, 0.f);
            hl[(kq * 4 + r) * 72 + nt * 16 + cn] = (_Float16)hv;
        }
    }

    // ---- [y2 | z] = h @ [W2_l | W2_r]: 4 MFMA ----
    h8v a2[2];
    a2[0] = *(const h8v*)(hl + cn * 72 + kq * 8);
    a2[1] = *(const h8v*)(hl + cn * 72 + 32 + kq * 8);
    f4v acc2[2] = { zero, zero };
    #pragma unroll
    for (int nt = 0; nt < 2; ++nt) {
        #pragma unroll
        for (int kt = 0; kt < 2; ++kt) {
            h8v bf = *(const h8v*)(B2 + ((kt * 2 + nt) * 64 + l) * 8);
            acc2[nt] = __builtin_amdgcn_mfma_f32_16x16x32_f16(a2[kt], bf, acc2[nt], 0, 0, 0);
        }
    }
    const float bz = b2[cn];
    #pragma unroll
    for (int r = 0; r < 4; ++r) {
        const int row = n0 + kq * 4 + r;
        if (row < N_NODES) {
            y2f[row * 16 + cn] = (_Float16)acc2[0][r];
            z[row * 16 + cn] = acc2[1][r] + bz;
        }
    }
}

// ---------------------------------------------------------------------------
// Layer 2: gather-mean of f16 y2 (32B rows; c2 = t&1 half, p2 = t>>1 slot;
// 4 nodes/wave) with packed-f16 accumulation, + z -> out.
// ---------------------------------------------------------------------------
__global__ __launch_bounds__(256) void layer2_kernel(
        const _Float16* __restrict__ y2f,
        const float* __restrict__ z,
        const int* __restrict__ rowptr,
        const int* __restrict__ csr_src,
        float* __restrict__ out) {
    const int wv = blockIdx.x * 4 + (threadIdx.x >> 6);
    const int l = threadIdx.x & 63;
    const int n = wv * 4 + (l >> 4);
    const int t = l & 15;
    const int c2 = t & 1;
    const int p2 = t >> 1;

    const int beg = rowptr[n];
    const int end = rowptr[n + 1];
    const int deg = end - beg;
    const int chunk = (deg + 7) >> 3;

    H2U a0, a1, a2, a3;
    a0.u = a1.u = a2.u = a3.u = 0;
    {
        int i = beg + p2 * chunk;
        const int ce = min(i + chunk, end);
        for (; i + 1 < ce; i += 2) {
            const int p = csr_src[i];
            const int q = csr_src[i + 1];
            uint4 up = *(const uint4*)(y2f + p * 16 + c2 * 8);
            uint4 uq = *(const uint4*)(y2f + q * 16 + c2 * 8);
            H2U r;
            r.u = up.x; a0.h += r.h;  r.u = uq.x; a0.h += r.h;
            r.u = up.y; a1.h += r.h;  r.u = uq.y; a1.h += r.h;
            r.u = up.z; a2.h += r.h;  r.u = uq.z; a2.h += r.h;
            r.u = up.w; a3.h += r.h;  r.u = uq.w; a3.h += r.h;
        }
        if (i < ce) {
            const int p = csr_src[i];
            uint4 up = *(const uint4*)(y2f + p * 16 + c2 * 8);
            H2U r;
            r.u = up.x; a0.h += r.h;
            r.u = up.y; a1.h += r.h;
            r.u = up.z; a2.h += r.h;
            r.u = up.w; a3.h += r.h;
        }
    }
    #pragma unroll
    for (int off = 2; off <= 8; off <<= 1) {
        H2U r;
        r.u = (unsigned)__shfl_xor((int)a0.u, off); a0.h += r.h;
        r.u = (unsigned)__shfl_xor((int)a1.u, off); a1.h += r.h;
        r.u = (unsigned)__shfl_xor((int)a2.u, off); a2.h += r.h;
        r.u = (unsigned)__shfl_xor((int)a3.u, off); a3.h += r.h;
    }
    if (p2 == 0) {
        const float rdeg = 1.0f / fmaxf((float)deg, 1.0f);
        const float4 z0 = *(const float4*)(z + n * 16 + c2 * 8);
        const float4 z1 = *(const float4*)(z + n * 16 + c2 * 8 + 4);
        float4 o0 = { (float)a0.h[0] * rdeg + z0.x, (float)a0.h[1] * rdeg + z0.y,
                      (float)a1.h[0] * rdeg + z0.z, (float)a1.h[1] * rdeg + z0.w };
        float4 o1 = { (float)a2.h[0] * rdeg + z1.x, (float)a2.h[1] * rdeg + z1.y,
                      (float)a3.h[0] * rdeg + z1.z, (float)a3.h[1] * rdeg + z1.w };
        *(float4*)(out + n * 16 + c2 * 8) = o0;
        *(float4*)(out + n * 16 + c2 * 8 + 4) = o1;
    }
}

extern "C" void kernel_launch(void* const* d_in, const int* in_sizes, int n_in,
                              void* d_out, int out_size, void* d_ws, size_t ws_size,
                              hipStream_t stream) {
    const float* x    = (const float*)d_in[0];
    const int*   ei   = (const int*)d_in[1];   // [2, 800000]: row 0 = src, row 1 = dst
    const float* W1_l = (const float*)d_in[2];
    const float* b1   = (const float*)d_in[3];
    const float* W1_r = (const float*)d_in[4];
    const float* W2_l = (const float*)d_in[5];
    const float* b2   = (const float*)d_in[6];
    const float* W2_r = (const float*)d_in[7];
    float* out = (float*)d_out;

    const int* src = ei;
    const int* dst = ei + N_EDGES;

    // Workspace layout (4-byte units):
    int* ws = (int*)d_ws;
    int*   histT   = ws;                              // SCAN_N = 50176
    int*   offT    = histT + SCAN_N;                  // 50176
    int*   rowptr  = offT  + SCAN_N;                  // 50001 (pad 50056)
    int*   bbuf    = rowptr + 50056;                  // 800,000 packed edges
    int*   csr_src = bbuf + 800000;                   // 800,000
    _Float16* xf    = (_Float16*)(csr_src + 800000);  // 3,203,072 f16 (50048 rows)
    _Float16* B1    = xf + 3203072;                   // 8,192 f16
    _Float16* B2    = B1 + 8192;                      // 2,048 f16
    _Float16* y2f   = B2 + 2048;                      // 800,000 f16
    float*    z     = (float*)(y2f + 800000);         // 800,000 f32
    // total ~19 MB

    hipMemsetAsync(histT, 0, SCAN_N * sizeof(int), stream);

    prep_kernel<<<3125, 256, 0, stream>>>(x, W1_l, W1_r, W2_l, W2_r, xf, B1, B2);
    count_kernel<<<G, 512, 0, stream>>>(dst, histT);
    scan_kernel<<<SCAN_BLOCKS, 256, 0, stream>>>(histT, offT);
    scatter_kernel<<<G, 512, 0, stream>>>(src, dst, offT, bbuf);
    build_kernel<<<NB, 256, 0, stream>>>(offT, bbuf, csr_src, rowptr);
    layer1_kernel<<<(N_NODES + 63) / 64, 256, 0, stream>>>(xf, rowptr, csr_src,
                                                           B1, B2, b1, b2, y2f, z);
    layer2_kernel<<<N_NODES / 16, 256, 0, stream>>>(y2f, z, rowptr, csr_src, out);
}

// Round 13
// 148.611 us; speedup vs baseline: 1.0006x; 1.0006x over previous
//
#include <hip/hip_runtime.h>

#define N_NODES 50000
#define N_EDGES 800000
#define NB      391            // buckets: dst>>7 (128 nodes each)
#define NBP     392            // padded bucket count (pad col stays zero)
#define G       128            // partition blocks for count/scatter
#define SCAN_N  (NBP * G)      // 50176 = 49 * 1024
#define SCAN_BLOCKS 49
#define MAXB    3072           // max edges per bucket (mean 2046, sigma ~45)
#define IDXCAP  1024           // staged indices per wave (mean 256, ~48 sigma)

typedef _Float16 h2v __attribute__((ext_vector_type(2)));
typedef _Float16 h8v __attribute__((ext_vector_type(8)));
typedef float    f4v __attribute__((ext_vector_type(4)));

union H2U { h2v h; unsigned u; };            // packed f16 pair <-> dword
union H8U { h8v v; unsigned u[4]; };         // 8 f16 <-> 4 dwords

// ---------------------------------------------------------------------------
// Prep: cast x -> f16 + pack W1/W2 into MFMA B-fragment order (block 0 only).
// B-frag (16x16x32 f16): lane holds 8 f16 B[k=32kt+(lane>>4)*8+j][n=16nt+(lane&15)].
// ---------------------------------------------------------------------------
__global__ void prep_kernel(const float* __restrict__ x,
                            const float* __restrict__ W1_l,
                            const float* __restrict__ W1_r,
                            const float* __restrict__ W2_l,
                            const float* __restrict__ W2_r,
                            _Float16* __restrict__ xf,
                            _Float16* __restrict__ B1,
                            _Float16* __restrict__ B2) {
    const int tid = blockIdx.x * 256 + threadIdx.x;      // < 800000
    {   // cast 4 floats -> 4 f16
        float4 v = *(const float4*)(x + tid * 4);
        H2U a, b;
        a.h = h2v{ (_Float16)v.x, (_Float16)v.y };
        b.h = h2v{ (_Float16)v.z, (_Float16)v.w };
        uint2 o = { a.u, b.u };
        *(uint2*)(xf + tid * 4) = o;
    }
    if (blockIdx.x == 0) {
        const int t = threadIdx.x;
        // B1: [W1_l; W1_r] (128 x 64), 16 frags (kt 0..3, nt 0..3)
        for (int p = t; p < 16 * 512; p += 256) {
            const int frag = p >> 9, lane = (p >> 3) & 63, j = p & 7;
            const int kt = frag >> 2, nt = frag & 3;
            const int k = kt * 32 + (lane >> 4) * 8 + j;
            const int n = nt * 16 + (lane & 15);
            const float w = (k < 64) ? W1_l[k * 64 + n] : W1_r[(k - 64) * 64 + n];
            B1[p] = (_Float16)w;
        }
        // B2: [W2_l | W2_r] (64 x 32), 4 frags (kt 0..1, nt 0..1)
        for (int p = t; p < 4 * 512; p += 256) {
            const int frag = p >> 9, lane = (p >> 3) & 63, j = p & 7;
            const int kt = frag >> 1, nt = frag & 1;
            const int k = kt * 32 + (lane >> 4) * 8 + j;
            const int n = lane & 15;
            const float w = (nt == 0) ? W2_l[k * 16 + n] : W2_r[k * 16 + n];
            B2[p] = (_Float16)w;
        }
    }
}

// ---------------------------------------------------------------------------
// Partition pass 1: per-block LDS histogram of dst buckets, written
// TRANSPOSED (histT[bucket*G + block]) so the fused scan reads linearly.
// ---------------------------------------------------------------------------
__global__ __launch_bounds__(512) void count_kernel(const int* __restrict__ dst,
                                                    int* __restrict__ histT) {
    __shared__ int hist[NBP];
    const int b = blockIdx.x, t = threadIdx.x;
    for (int i = t; i < NBP; i += 512) hist[i] = 0;
    __syncthreads();
    for (int i4 = b * 512 + t; i4 < N_EDGES / 4; i4 += G * 512) {
        int4 d = *(const int4*)(dst + i4 * 4);
        atomicAdd(&hist[d.x >> 7], 1);
        atomicAdd(&hist[d.y >> 7], 1);
        atomicAdd(&hist[d.z >> 7], 1);
        atomicAdd(&hist[d.w >> 7], 1);
    }
    __syncthreads();
    for (int i = t; i < NB; i += 512) histT[i * G + b] = hist[i];
}

// ---------------------------------------------------------------------------
// Fused scan: block b computes its base by summing histT[0 .. b*1024)
// coalesced, then LDS-scans its own 1024-elem chunk and emits offT.
// ---------------------------------------------------------------------------
__global__ void scan_kernel(const int* __restrict__ histT,
                            int* __restrict__ offT) {
    __shared__ int redu[256];
    __shared__ int lds[256];
    const int b = blockIdx.x, t = threadIdx.x;

    int part = 0;
    for (int j = t * 4; j < b * 1024; j += 1024) {
        int4 v = *(const int4*)(histT + j);
        part += v.x + v.y + v.z + v.w;
    }
    redu[t] = part;
    __syncthreads();
    for (int off = 128; off > 0; off >>= 1) {
        if (t < off) redu[t] += redu[t + off];
        __syncthreads();
    }
    const int base = redu[0];

    const int idx = b * 1024 + t * 4;
    int4 v = *(const int4*)(histT + idx);
    const int s = v.x + v.y + v.z + v.w;
    lds[t] = s;
    __syncthreads();
    for (int off = 1; off < 256; off <<= 1) {
        int u = (t >= off) ? lds[t - off] : 0;
        __syncthreads();
        lds[t] += u;
        __syncthreads();
    }
    const int excl = base + lds[t] - s;
    int4 o = { excl, excl + v.x, excl + v.x + v.y, excl + v.x + v.y + v.z };
    *(int4*)(offT + idx) = o;
}

// ---------------------------------------------------------------------------
// Partition pass 2: scatter edges to exact positions via LDS cursors seeded
// from offT — zero global atomics. Packs (dst&127)<<16 | src.
// ---------------------------------------------------------------------------
__global__ __launch_bounds__(512) void scatter_kernel(const int* __restrict__ src,
                                                      const int* __restrict__ dst,
                                                      const int* __restrict__ offT,
                                                      int* __restrict__ bbuf) {
    __shared__ int cur[NB];
    const int b = blockIdx.x, t = threadIdx.x;
    for (int i = t; i < NB; i += 512) cur[i] = offT[i * G + b];
    __syncthreads();
    for (int i4 = b * 512 + t; i4 < N_EDGES / 4; i4 += G * 512) {
        int4 s = *(const int4*)(src + i4 * 4);
        int4 d = *(const int4*)(dst + i4 * 4);
        #pragma unroll
        for (int q = 0; q < 4; ++q) {
            const int dv = (q == 0) ? d.x : (q == 1) ? d.y : (q == 2) ? d.z : d.w;
            const int sv = (q == 0) ? s.x : (q == 1) ? s.y : (q == 2) ? s.z : s.w;
            const int pos = atomicAdd(&cur[dv >> 7], 1);
            bbuf[pos] = ((dv & 127) << 16) | sv;
        }
    }
}

// ---------------------------------------------------------------------------
// Build: one workgroup per bucket. Contiguous read of the bucket's packed
// edges, LDS hist over 128 local nodes, LDS scan -> rowptr, LDS scatter,
// fully-coalesced csr_src write-out.
// ---------------------------------------------------------------------------
__global__ __launch_bounds__(256) void build_kernel(
        const int* __restrict__ offT,
        const int* __restrict__ bbuf,
        int* __restrict__ csr_src,
        int* __restrict__ rowptr) {
    __shared__ int stash[MAXB];
    __shared__ int lcsr[MAXB];
    __shared__ int hist[128];
    __shared__ int cur[128];

    const int b = blockIdx.x, t = threadIdx.x;
    const int start = offT[b * G];
    const int end = offT[(b + 1) * G];     // valid for b=NB-1 via pad bucket
    const int cnt_b = min(end - start, MAXB);

    if (t < 128) hist[t] = 0;
    __syncthreads();

    for (int i = t; i < cnt_b; i += 256) {
        const int w = bbuf[start + i];
        stash[i] = w;
        atomicAdd(&hist[w >> 16], 1);
    }
    __syncthreads();

    const int orig = (t < 128) ? hist[t] : 0;
    for (int off = 1; off < 128; off <<= 1) {
        int v = (t >= off && t < 128) ? hist[t - off] : 0;
        __syncthreads();
        if (t < 128) hist[t] += v;
        __syncthreads();
    }
    if (t < 128) cur[t] = hist[t] - orig;    // exclusive
    __syncthreads();

    const int node = b * 128 + t;
    if (t < 128 && node < N_NODES) rowptr[node] = start + cur[t];
    if (b == NB - 1 && t == 0) rowptr[N_NODES] = N_EDGES;

    for (int i = t; i < cnt_b; i += 256) {
        const int w = stash[i];
        const int p = atomicAdd(&cur[w >> 16], 1);
        lcsr[p] = w & 0xFFFF;
    }
    __syncthreads();

    for (int i = t; i < cnt_b; i += 256) csr_src[start + i] = lcsr[i];
}

// ---------------------------------------------------------------------------
// FUSED layer 1 (gather + MLP), R13: LDS-staged indices + unroll-4 gather.
// One wave = 16 consecutive nodes -> their CSR entries form ONE contiguous
// run; the wave stages it into LDS coalesced. The per-lane gather loop then
// reads indices from LDS (no global latency in the address chain) and issues
// 4 neighbor rows (8 uint4 loads) back-to-back per iteration.
// Lane l: cn = l&15 (node in tile), kq = l>>4 (feature quad). Mean lands
// directly in MFMA A-registers. 16 MFMA (B1) -> h -> LDS -> 4 MFMA (B2).
// R10 lesson: per-lane register accumulation; NEVER per-edge LDS atomics.
// ---------------------------------------------------------------------------
__global__ __launch_bounds__(256) void layer1_kernel(
        const _Float16* __restrict__ xf,
        const int* __restrict__ rowptr,
        const int* __restrict__ csr_src,
        const _Float16* __restrict__ B1,
        const _Float16* __restrict__ B2,
        const float* __restrict__ b1,
        const float* __restrict__ b2,
        _Float16* __restrict__ y2f,
        float* __restrict__ z) {
    __shared__ _Float16 hlds[4][16 * 72];
    __shared__ int idxs[4][IDXCAP];
    const int widx = threadIdx.x >> 6;
    const int l = threadIdx.x & 63;
    const int cn = l & 15;
    const int kq = l >> 4;
    const int n0 = (blockIdx.x * 4 + widx) * 16;
    const int ng = n0 + cn;                 // this lane's gather node

    // ---- stage this wave's contiguous CSR run into LDS (coalesced) ----
    const int wbeg = rowptr[min(n0, N_NODES)];
    const int wend = rowptr[min(n0 + 16, N_NODES)];
    const int total = wend - wbeg;
    const int sc = min(total, IDXCAP);
    for (int j = l; j < sc; j += 64) idxs[widx][j] = csr_src[wbeg + j];
    __syncthreads();   // all 4 waves pass unconditionally

    int o0 = 0, o1 = 0;
    if (ng < N_NODES) {
        o0 = rowptr[ng] - wbeg;
        o1 = rowptr[ng + 1] - wbeg;
    }

    // ---- gather: accumulate this lane's A-fragment features, 4 rows deep ----
    H2U lo[4], hi[4];
    #pragma unroll
    for (int j = 0; j < 4; ++j) { lo[j].u = 0; hi[j].u = 0; }
    const _Float16* xq = xf + kq * 8;
    const int* iw = &idxs[widx][0];
    int i = o0;
    for (; i + 3 < o1; i += 4) {
        const int s0 = (i     < sc) ? iw[i]     : csr_src[wbeg + i];
        const int s1 = (i + 1 < sc) ? iw[i + 1] : csr_src[wbeg + i + 1];
        const int s2 = (i + 2 < sc) ? iw[i + 2] : csr_src[wbeg + i + 2];
        const int s3 = (i + 3 < sc) ? iw[i + 3] : csr_src[wbeg + i + 3];
        const uint4 u0 = *(const uint4*)(xq + s0 * 64);
        const uint4 v0 = *(const uint4*)(xq + s0 * 64 + 32);
        const uint4 u1 = *(const uint4*)(xq + s1 * 64);
        const uint4 v1 = *(const uint4*)(xq + s1 * 64 + 32);
        const uint4 u2 = *(const uint4*)(xq + s2 * 64);
        const uint4 v2 = *(const uint4*)(xq + s2 * 64 + 32);
        const uint4 u3 = *(const uint4*)(xq + s3 * 64);
        const uint4 v3 = *(const uint4*)(xq + s3 * 64 + 32);
        H2U t;
        t.u = u0.x; lo[0].h += t.h;  t.u = u1.x; lo[0].h += t.h;
        t.u = u2.x; lo[0].h += t.h;  t.u = u3.x; lo[0].h += t.h;
        t.u = u0.y; lo[1].h += t.h;  t.u = u1.y; lo[1].h += t.h;
        t.u = u2.y; lo[1].h += t.h;  t.u = u3.y; lo[1].h += t.h;
        t.u = u0.z; lo[2].h += t.h;  t.u = u1.z; lo[2].h += t.h;
        t.u = u2.z; lo[2].h += t.h;  t.u = u3.z; lo[2].h += t.h;
        t.u = u0.w; lo[3].h += t.h;  t.u = u1.w; lo[3].h += t.h;
        t.u = u2.w; lo[3].h += t.h;  t.u = u3.w; lo[3].h += t.h;
        t.u = v0.x; hi[0].h += t.h;  t.u = v1.x; hi[0].h += t.h;
        t.u = v2.x; hi[0].h += t.h;  t.u = v3.x; hi[0].h += t.h;
        t.u = v0.y; hi[1].h += t.h;  t.u = v1.y; hi[1].h += t.h;
        t.u = v2.y; hi[1].h += t.h;  t.u = v3.y; hi[1].h += t.h;
        t.u = v0.z; hi[2].h += t.h;  t.u = v1.z; hi[2].h += t.h;
        t.u = v2.z; hi[2].h += t.h;  t.u = v3.z; hi[2].h += t.h;
        t.u = v0.w; hi[3].h += t.h;  t.u = v1.w; hi[3].h += t.h;
        t.u = v2.w; hi[3].h += t.h;  t.u = v3.w; hi[3].h += t.h;
    }
    for (; i < o1; ++i) {
        const int s0 = (i < sc) ? iw[i] : csr_src[wbeg + i];
        const uint4 u0 = *(const uint4*)(xq + s0 * 64);
        const uint4 v0 = *(const uint4*)(xq + s0 * 64 + 32);
        H2U t;
        t.u = u0.x; lo[0].h += t.h;  t.u = v0.x; hi[0].h += t.h;
        t.u = u0.y; lo[1].h += t.h;  t.u = v0.y; hi[1].h += t.h;
        t.u = u0.z; lo[2].h += t.h;  t.u = v0.z; hi[2].h += t.h;
        t.u = u0.w; lo[3].h += t.h;  t.u = v0.w; hi[3].h += t.h;
    }
    const int deg = o1 - o0;
    const float rdeg = 1.0f / fmaxf((float)deg, 1.0f);
    const _Float16 rh = (_Float16)rdeg;
    const h2v rd2 = { rh, rh };
    H8U af0, af1, af2, af3;
    #pragma unroll
    for (int j = 0; j < 4; ++j) {
        lo[j].h *= rd2; hi[j].h *= rd2;
        af0.u[j] = lo[j].u;
        af1.u[j] = hi[j].u;
    }
    {   // self row (xf padded to 50048 rows so ng<50048 reads are in-bounds)
        const uint4 su = *(const uint4*)(xf + ng * 64 + kq * 8);
        const uint4 sv = *(const uint4*)(xf + ng * 64 + 32 + kq * 8);
        af2.u[0] = su.x; af2.u[1] = su.y; af2.u[2] = su.z; af2.u[3] = su.w;
        af3.u[0] = sv.x; af3.u[1] = sv.y; af3.u[2] = sv.z; af3.u[3] = sv.w;
    }

    // ---- h = relu([mean|x] @ [W1_l;W1_r] + b1): 16 MFMA ----
    const f4v zero = { 0.f, 0.f, 0.f, 0.f };
    f4v acc[4] = { zero, zero, zero, zero };
    #pragma unroll
    for (int nt = 0; nt < 4; ++nt) {
        acc[nt] = __builtin_amdgcn_mfma_f32_16x16x32_f16(af0.v, *(const h8v*)(B1 + ((0 * 4 + nt) * 64 + l) * 8), acc[nt], 0, 0, 0);
        acc[nt] = __builtin_amdgcn_mfma_f32_16x16x32_f16(af1.v, *(const h8v*)(B1 + ((1 * 4 + nt) * 64 + l) * 8), acc[nt], 0, 0, 0);
        acc[nt] = __builtin_amdgcn_mfma_f32_16x16x32_f16(af2.v, *(const h8v*)(B1 + ((2 * 4 + nt) * 64 + l) * 8), acc[nt], 0, 0, 0);
        acc[nt] = __builtin_amdgcn_mfma_f32_16x16x32_f16(af3.v, *(const h8v*)(B1 + ((3 * 4 + nt) * 64 + l) * 8), acc[nt], 0, 0, 0);
    }

    _Float16* hl = &hlds[widx][0];
    #pragma unroll
    for (int nt = 0; nt < 4; ++nt) {
        const float bias = b1[nt * 16 + cn];
        #pragma unroll
        for (int r = 0; r < 4; ++r) {
            const float hv = fmaxf(acc[nt][r] + bias, 0.f);
            hl[(kq * 4 + r) * 72 + nt * 16 + cn] = (_Float16)hv;
        }
    }

    // ---- [y2 | z] = h @ [W2_l | W2_r]: 4 MFMA ----
    h8v a2[2];
    a2[0] = *(const h8v*)(hl + cn * 72 + kq * 8);
    a2[1] = *(const h8v*)(hl + cn * 72 + 32 + kq * 8);
    f4v acc2[2] = { zero, zero };
    #pragma unroll
    for (int nt = 0; nt < 2; ++nt) {
        #pragma unroll
        for (int kt = 0; kt < 2; ++kt) {
            h8v bf = *(const h8v*)(B2 + ((kt * 2 + nt) * 64 + l) * 8);
            acc2[nt] = __builtin_amdgcn_mfma_f32_16x16x32_f16(a2[kt], bf, acc2[nt], 0, 0, 0);
        }
    }
    const float bz = b2[cn];
    #pragma unroll
    for (int r = 0; r < 4; ++r) {
        const int row = n0 + kq * 4 + r;
        if (row < N_NODES) {
            y2f[row * 16 + cn] = (_Float16)acc2[0][r];
            z[row * 16 + cn] = acc2[1][r] + bz;
        }
    }
}

// ---------------------------------------------------------------------------
// Layer 2: gather-mean of f16 y2 (32B rows; c2 = t&1 half, p2 = t>>1 slot;
// 4 nodes/wave) with packed-f16 accumulation, + z -> out.
// ---------------------------------------------------------------------------
__global__ __launch_bounds__(256) void layer2_kernel(
        const _Float16* __restrict__ y2f,
        const float* __restrict__ z,
        const int* __restrict__ rowptr,
        const int* __restrict__ csr_src,
        float* __restrict__ out) {
    const int wv = blockIdx.x * 4 + (threadIdx.x >> 6);
    const int l = threadIdx.x & 63;
    const int n = wv * 4 + (l >> 4);
    const int t = l & 15;
    const int c2 = t & 1;
    const int p2 = t >> 1;

    const int beg = rowptr[n];
    const int end = rowptr[n + 1];
    const int deg = end - beg;
    const int chunk = (deg + 7) >> 3;

    H2U a0, a1, a2, a3;
    a0.u = a1.u = a2.u = a3.u = 0;
    {
        int i = beg + p2 * chunk;
        const int ce = min(i + chunk, end);
        for (; i + 1 < ce; i += 2) {
            const int p = csr_src[i];
            const int q = csr_src[i + 1];
            uint4 up = *(const uint4*)(y2f + p * 16 + c2 * 8);
            uint4 uq = *(const uint4*)(y2f + q * 16 + c2 * 8);
            H2U r;
            r.u = up.x; a0.h += r.h;  r.u = uq.x; a0.h += r.h;
            r.u = up.y; a1.h += r.h;  r.u = uq.y; a1.h += r.h;
            r.u = up.z; a2.h += r.h;  r.u = uq.z; a2.h += r.h;
            r.u = up.w; a3.h += r.h;  r.u = uq.w; a3.h += r.h;
        }
        if (i < ce) {
            const int p = csr_src[i];
            uint4 up = *(const uint4*)(y2f + p * 16 + c2 * 8);
            H2U r;
            r.u = up.x; a0.h += r.h;
            r.u = up.y; a1.h += r.h;
            r.u = up.z; a2.h += r.h;
            r.u = up.w; a3.h += r.h;
        }
    }
    #pragma unroll
    for (int off = 2; off <= 8; off <<= 1) {
        H2U r;
        r.u = (unsigned)__shfl_xor((int)a0.u, off); a0.h += r.h;
        r.u = (unsigned)__shfl_xor((int)a1.u, off); a1.h += r.h;
        r.u = (unsigned)__shfl_xor((int)a2.u, off); a2.h += r.h;
        r.u = (unsigned)__shfl_xor((int)a3.u, off); a3.h += r.h;
    }
    if (p2 == 0) {
        const float rdeg = 1.0f / fmaxf((float)deg, 1.0f);
        const float4 z0 = *(const float4*)(z + n * 16 + c2 * 8);
        const float4 z1 = *(const float4*)(z + n * 16 + c2 * 8 + 4);
        float4 o0 = { (float)a0.h[0] * rdeg + z0.x, (float)a0.h[1] * rdeg + z0.y,
                      (float)a1.h[0] * rdeg + z0.z, (float)a1.h[1] * rdeg + z0.w };
        float4 o1 = { (float)a2.h[0] * rdeg + z1.x, (float)a2.h[1] * rdeg + z1.y,
                      (float)a3.h[0] * rdeg + z1.z, (float)a3.h[1] * rdeg + z1.w };
        *(float4*)(out + n * 16 + c2 * 8) = o0;
        *(float4*)(out + n * 16 + c2 * 8 + 4) = o1;
    }
}

extern "C" void kernel_launch(void* const* d_in, const int* in_sizes, int n_in,
                              void* d_out, int out_size, void* d_ws, size_t ws_size,
                              hipStream_t stream) {
    const float* x    = (const float*)d_in[0];
    const int*   ei   = (const int*)d_in[1];   // [2, 800000]: row 0 = src, row 1 = dst
    const float* W1_l = (const float*)d_in[2];
    const float* b1   = (const float*)d_in[3];
    const float* W1_r = (const float*)d_in[4];
    const float* W2_l = (const float*)d_in[5];
    const float* b2   = (const float*)d_in[6];
    const float* W2_r = (const float*)d_in[7];
    float* out = (float*)d_out;

    const int* src = ei;
    const int* dst = ei + N_EDGES;

    // Workspace layout (4-byte units):
    int* ws = (int*)d_ws;
    int*   histT   = ws;                              // SCAN_N = 50176
    int*   offT    = histT + SCAN_N;                  // 50176
    int*   rowptr  = offT  + SCAN_N;                  // 50001 (pad 50056)
    int*   bbuf    = rowptr + 50056;                  // 800,000 packed edges
    int*   csr_src = bbuf + 800000;                   // 800,000
    _Float16* xf    = (_Float16*)(csr_src + 800000);  // 3,203,072 f16 (50048 rows)
    _Float16* B1    = xf + 3203072;                   // 8,192 f16
    _Float16* B2    = B1 + 8192;                      // 2,048 f16
    _Float16* y2f   = B2 + 2048;                      // 800,000 f16
    float*    z     = (float*)(y2f + 800000);         // 800,000 f32
    // total ~19 MB

    hipMemsetAsync(histT, 0, SCAN_N * sizeof(int), stream);

    prep_kernel<<<3125, 256, 0, stream>>>(x, W1_l, W1_r, W2_l, W2_r, xf, B1, B2);
    count_kernel<<<G, 512, 0, stream>>>(dst, histT);
    scan_kernel<<<SCAN_BLOCKS, 256, 0, stream>>>(histT, offT);
    scatter_kernel<<<G, 512, 0, stream>>>(src, dst, offT, bbuf);
    build_kernel<<<NB, 256, 0, stream>>>(offT, bbuf, csr_src, rowptr);
    layer1_kernel<<<(N_NODES + 63) / 64, 256, 0, stream>>>(xf, rowptr, csr_src,
                                                           B1, B2, b1, b2, y2f, z);
    layer2_kernel<<<N_NODES / 16, 256, 0, stream>>>(y2f, z, rowptr, csr_src, out);
}